// Round 9
// baseline (77.634 us; speedup 1.0000x reference)
//
#include <hip/hip_runtime.h>
#include <hip/hip_bf16.h>
#include <math.h>

#define HW 16384          // 128*128
#define IMG 128
#define C_IN 128
#define C_OUT 64
#define NB 8
#define NE 4

typedef __attribute__((ext_vector_type(8))) short bf16x8;
typedef __attribute__((ext_vector_type(4))) float f32x4;

static __device__ __forceinline__ float bf2f_u(unsigned hbits) {
  union { unsigned u; float f; } v; v.u = hbits << 16;
  return v.f;
}
static __device__ __forceinline__ float bf2f(unsigned short h) {
  return bf2f_u((unsigned)h);
}
// HW packed conversion: two f32 -> one u32 of 2 bf16 (RNE, v_cvt_pk_bf16_f32)
static __device__ __forceinline__ unsigned cvtpk(float a, float b) {
  __hip_bfloat162 p = __float22bfloat162_rn(make_float2(a, b));
  union { __hip_bfloat162 h; unsigned u; } v; v.h = p;
  return v.u;
}
// Dekker split of a float pair: hi = RNE bf16 pair, lo = RNE bf16 of residuals
static __device__ __forceinline__ void pk2(float a, float b,
                                           unsigned& hi, unsigned& lo) {
  hi = cvtpk(a, b);
  float ra = a - bf2f_u(hi & 0xFFFFu);
  float rb = b - bf2f_u(hi >> 16);
  lo = cvtpk(ra, rb);
}

union FragU { unsigned u[4]; uint4 q; bf16x8 v; };

// ---- K0: precompute W MFMA fragments (hi/lo bf16), block-invariant ----
// layout: whi/wlo[(k*4+ot)*64 + lane], lane=(kg<<4)|rowb
__global__ __launch_bounds__(64) void wfrag_kernel(
    const float* __restrict__ pre_w, uint4* __restrict__ whi,
    uint4* __restrict__ wlo) {
  int lane = threadIdx.x;
  int rowb = lane & 15, kg = lane >> 4;
  for (int q = 0; q < 16; ++q) {          // q = k*4 + ot
    int k = q >> 2, ot = q & 3;
    const float* wp = pre_w + (ot * 16 + rowb) * C_IN + k * 32 + kg * 8;
    float4 a = *(const float4*)wp;
    float4 c = *(const float4*)(wp + 4);
    uint4 h, l;
    pk2(a.x, a.y, h.x, l.x);
    pk2(a.z, a.w, h.y, l.y);
    pk2(c.x, c.y, h.z, l.z);
    pk2(c.z, c.w, h.w, l.w);
    whi[q * 64 + lane] = h;
    wlo[q * 64 + lane] = l;
  }
}

// ---- K1: pre-fuse 1x1 conv as MFMA GEMM + fused pooling partials ----
// 1 wave per block; block = one 32-px strip x all 64 outputs.
// 3-term Dekker MFMA: hi*whi + lo*whi + hi*wlo (err ~2^-16).
__global__ __launch_bounds__(64, 4) void prefuse_mfma(
    const float* __restrict__ x, const uint4* __restrict__ whi,
    const uint4* __restrict__ wlo, const float* __restrict__ pre_b,
    unsigned short* __restrict__ x1, float* __restrict__ pmax,
    float* __restrict__ psum) {
  __shared__ unsigned short tbuf[16][72];   // [o_loc][px + pad]
  int lane = threadIdx.x;
  int rowb = lane & 15;                     // A-row(px) / B-col(o) index
  int kg = lane >> 4;                       // k-group 0..3
  int blk = blockIdx.x;                     // 4096
  int b = blk >> 9;
  int strip = blk & 511;
  int px0 = strip << 5;                     // 32 px per strip

  f32x4 acc[2][4];                          // [px-tile][o-tile]
#pragma unroll
  for (int ot = 0; ot < 4; ++ot) {
    float t = pre_b[ot * 16 + rowb];        // bias per D-col (=o)
#pragma unroll
    for (int pt = 0; pt < 2; ++pt) acc[pt][ot] = (f32x4){t, t, t, t};
  }

  for (int k = 0; k < 4; ++k) {
    FragU wh[4], wl[4];
#pragma unroll
    for (int ot = 0; ot < 4; ++ot) {
      wh[ot].q = whi[(k * 4 + ot) * 64 + lane];
      wl[ot].q = wlo[(k * 4 + ot) * 64 + lane];
    }
#pragma unroll
    for (int pt = 0; pt < 2; ++pt) {
      // A-frag (X): lane holds X[c0+kg*8+j][px0+pt*16+rowb]
      const float* ap = x + ((size_t)b * C_IN + k * 32 + kg * 8) * HW
                          + px0 + pt * 16 + rowb;
      float xv[8];
#pragma unroll
      for (int j = 0; j < 8; ++j) xv[j] = ap[(size_t)j * HW];
      FragU h, l;
      pk2(xv[0], xv[1], h.u[0], l.u[0]);
      pk2(xv[2], xv[3], h.u[1], l.u[1]);
      pk2(xv[4], xv[5], h.u[2], l.u[2]);
      pk2(xv[6], xv[7], h.u[3], l.u[3]);
#pragma unroll
      for (int ot = 0; ot < 4; ++ot) {
        acc[pt][ot] = __builtin_amdgcn_mfma_f32_16x16x32_bf16(h.v, wh[ot].v, acc[pt][ot], 0, 0, 0);
        acc[pt][ot] = __builtin_amdgcn_mfma_f32_16x16x32_bf16(l.v, wh[ot].v, acc[pt][ot], 0, 0, 0);
        acc[pt][ot] = __builtin_amdgcn_mfma_f32_16x16x32_bf16(h.v, wl[ot].v, acc[pt][ot], 0, 0, 0);
      }
    }
  }

  // epilogue per o-tile: pooling partials + LDS transpose -> bf16 x1 store
#pragma unroll
  for (int ot = 0; ot < 4; ++ot) {
    float m = -INFINITY, s = 0.f;
#pragma unroll
    for (int pt = 0; pt < 2; ++pt)
#pragma unroll
      for (int r = 0; r < 4; ++r) {
        float v = acc[pt][ot][r];
        m = fmaxf(m, v); s += v;
      }
    m = fmaxf(m, __shfl_xor(m, 16)); s += __shfl_xor(s, 16);
    m = fmaxf(m, __shfl_xor(m, 32)); s += __shfl_xor(s, 32);
    if (lane < 16) {
      int idx = strip * 512 + b * 64 + ot * 16 + lane;  // [strip][bo]
      pmax[idx] = m; psum[idx] = s;
    }
    // D: row(px) = pt*16 + kg*4 + r, col(o) = rowb
#pragma unroll
    for (int pt = 0; pt < 2; ++pt) {
      uint2 p;
      p.x = cvtpk(acc[pt][ot][0], acc[pt][ot][1]);
      p.y = cvtpk(acc[pt][ot][2], acc[pt][ot][3]);
      *(uint2*)&tbuf[rowb][pt * 16 + kg * 4] = p;
    }
    __syncthreads();  // 1-wave block: cheap; forces lgkmcnt drain + ordering
    uint4 val = *(const uint4*)&tbuf[lane >> 2][(lane & 3) * 8];
    unsigned short* op = x1 + ((size_t)b * C_OUT + ot * 16 + (lane >> 2)) * HW
                            + px0 + (lane & 3) * 8;
    *(uint4*)op = val;
    __syncthreads();  // WAR guard before next ot reuses tbuf
  }
}

// ---- K2: finish pooling: one block per (b,o) ----
__global__ __launch_bounds__(64) void pool2_kernel(
    const float* __restrict__ pmax, const float* __restrict__ psum,
    float* __restrict__ pooled) {
  int bo = blockIdx.x;       // 0..511
  int lane = threadIdx.x;
  float m = -INFINITY, s = 0.f;
#pragma unroll
  for (int i = 0; i < 8; ++i) {
    int strip = lane + (i << 6);
    m = fmaxf(m, pmax[strip * 512 + bo]);
    s += psum[strip * 512 + bo];
  }
#pragma unroll
  for (int d = 32; d >= 1; d >>= 1) {
    m = fmaxf(m, __shfl_xor(m, d));
    s += __shfl_xor(s, d);
  }
  if (lane == 0) pooled[bo] = m + s * (1.0f / HW);
}

// ---- K3: gate network -> cof[B][E] ----
__global__ __launch_bounds__(64) void gate_kernel(
    const float* __restrict__ pooled, const float* __restrict__ gw0,
    const float* __restrict__ gb0, const float* __restrict__ gw1,
    const float* __restrict__ gb1, float* __restrict__ cof) {
  int b = threadIdx.x;
  if (b >= NB) return;
  float logits[NE], noise[NE];
#pragma unroll
  for (int e = 0; e < NE; ++e) {
    float d0 = gb0[e], d1 = gb1[e];
    for (int k = 0; k < C_OUT; ++k) {
      float pv = pooled[b * C_OUT + k];
      d0 = fmaf(pv, gw0[e * C_OUT + k], d0);
      d1 = fmaf(pv, gw1[e * C_OUT + k], d1);
    }
    logits[e] = d1 > 0.f ? d1 : 0.2f * d1;
    noise[e] = log1pf(expf(d0));
  }
  float mn = 0.25f * (noise[0] + noise[1] + noise[2] + noise[3]);
  float var = 0.f;
#pragma unroll
  for (int e = 0; e < NE; ++e) { float d = noise[e] - mn; var += d * d; }
  float sd = sqrtf(var * (1.0f / 3.0f));
  float scores[NE];
#pragma unroll
  for (int e = 0; e < NE; ++e) scores[e] = logits[e] + (noise[e] - mn) / sd;
  int i0 = 0;
#pragma unroll
  for (int e = 1; e < NE; ++e) if (scores[e] > scores[i0]) i0 = e;
  int i1 = -1;
#pragma unroll
  for (int e = 0; e < NE; ++e)
    if (e != i0 && (i1 < 0 || scores[e] > scores[i1])) i1 = e;
  float mm = fmaxf(logits[i0], logits[i1]);
  float e0 = expf(logits[i0] - mm), e1 = expf(logits[i1] - mm);
  float inv = 1.0f / (e0 + e1);
#pragma unroll
  for (int e = 0; e < NE; ++e) cof[b * NE + e] = 0.f;
  cof[b * NE + i0] = e0 * inv;
  cof[b * NE + i1] = e1 * inv;
}

// ---- K4: fused experts, single pass over BOTH active experts ----
__global__ __launch_bounds__(256) void expert_kernel(
    const unsigned short* __restrict__ x1, const float* __restrict__ ew1,
    const float* __restrict__ eb1, const float* __restrict__ ew2,
    const float* __restrict__ eb2, const float* __restrict__ cof,
    float* __restrict__ out) {
  __shared__ float xs[36 * 36 + 8];
  __shared__ unsigned hs[34 * 36 + 8];     // packed (hA | hB<<16)
  int tid = threadIdx.x, blk = blockIdx.x;
  int tile = blk & 15, c = (blk >> 4) & 63, b = blk >> 10;
  int ty0 = (tile >> 2) * 32, tx0 = (tile & 3) * 32;
  const unsigned short* xp = x1 + ((size_t)b * C_OUT + c) * HW;

  // the two active experts (uniform per block)
  int eA = -1, eB = -1; float cfA = 0.f, cfB = 0.f;
#pragma unroll
  for (int e = 0; e < NE; ++e) {
    float cv = cof[b * NE + e];
    if (cv != 0.f) { if (eA < 0) { eA = e; cfA = cv; } else { eB = e; cfB = cv; } }
  }
  if (eA < 0) { eA = 0; cfA = 0.f; }
  if (eB < 0) { eB = eA; cfB = 0.f; }

  float w1A[9], w1B[9], w2A[9], w2B[9];
#pragma unroll
  for (int t = 0; t < 9; ++t) {
    w1A[t] = ew1[((size_t)eA * C_OUT + c) * 9 + t];
    w1B[t] = ew1[((size_t)eB * C_OUT + c) * 9 + t];
    w2A[t] = cfA * ew2[((size_t)eA * C_OUT + c) * 9 + t];
    w2B[t] = cfB * ew2[((size_t)eB * C_OUT + c) * 9 + t];
  }
  float b1A = eb1[eA * C_OUT + c], b1B = eb1[eB * C_OUT + c];
  float bias2 = cfA * eb2[eA * C_OUT + c] + cfB * eb2[eB * C_OUT + c];

  // stage 36x36 x-tile (halo 2), zero outside image
  for (int i = tid; i < 36 * 36; i += 256) {
    int iy = i / 36, ix = i - iy * 36;
    int gy = ty0 - 2 + iy, gx = tx0 - 2 + ix;
    float v = 0.f;
    if ((unsigned)gy < 128u && (unsigned)gx < 128u) v = bf2f(xp[gy * IMG + gx]);
    xs[i] = v;
  }
  __syncthreads();

  // conv1 + gelu for BOTH experts; pack as bf16 pair
  for (int t = tid; t < 34 * 9; t += 256) {
    int hr = t / 9, g4 = t - hr * 9;
    int hc0 = g4 * 4;
    const float* xr = xs + hr * 36 + hc0;
    float xv[3][6];
#pragma unroll
    for (int dy = 0; dy < 3; ++dy) {
      float4 a = *(const float4*)(xr + dy * 36);
      float2 bb = *(const float2*)(xr + dy * 36 + 4);
      xv[dy][0] = a.x; xv[dy][1] = a.y; xv[dy][2] = a.z; xv[dy][3] = a.w;
      xv[dy][4] = bb.x; xv[dy][5] = bb.y;
    }
    int gy = ty0 - 1 + hr, gx0 = tx0 - 1 + hc0;
    uint4 hv; unsigned* hp4 = (unsigned*)&hv;
#pragma unroll
    for (int j = 0; j < 4; ++j) {
      float sA = b1A, sB = b1B;
#pragma unroll
      for (int dy = 0; dy < 3; ++dy)
#pragma unroll
        for (int dx = 0; dx < 3; ++dx) {
          float xvv = xv[dy][j + dx];
          sA = fmaf(xvv, w1A[dy * 3 + dx], sA);
          sB = fmaf(xvv, w1B[dy * 3 + dx], sB);
        }
      float uA = sA * sA, uB = sB * sB;
      float tA = 1.f - uA * (0.16666667f - uA * (0.025f - uA * 0.0029761905f));
      float tB = 1.f - uB * (0.16666667f - uB * (0.025f - uB * 0.0029761905f));
      float gA = sA * fmaf(0.3989422804f * sA, tA, 0.5f);
      float gB = sB * fmaf(0.3989422804f * sB, tB, 0.5f);
      bool ok = ((unsigned)gy < 128u) && ((unsigned)(gx0 + j) < 128u);
      hp4[j] = ok ? cvtpk(gA, gB) : 0u;
    }
    *(uint4*)(hs + hr * 36 + hc0) = hv;
  }
  __syncthreads();

  // conv2 combined: 4 outputs per thread
  int row2 = tid >> 3, oc0 = (tid & 7) * 4;
  const unsigned* hp = hs + row2 * 36 + oc0;
  float s0 = bias2, s1 = bias2, s2 = bias2, s3 = bias2;
#pragma unroll
  for (int dy = 0; dy < 3; ++dy) {
    uint4 a = *(const uint4*)(hp + dy * 36);
    uint2 bb = *(const uint2*)(hp + dy * 36 + 4);
    unsigned u[6] = {a.x, a.y, a.z, a.w, bb.x, bb.y};
    float hA[6], hB[6];
#pragma unroll
    for (int q = 0; q < 6; ++q) {
      hA[q] = bf2f_u(u[q] & 0xFFFFu);
      union { unsigned uu; float ff; } vb; vb.uu = u[q] & 0xFFFF0000u;
      hB[q] = vb.ff;
    }
    float wA0 = w2A[dy * 3], wA1 = w2A[dy * 3 + 1], wA2 = w2A[dy * 3 + 2];
    float wB0 = w2B[dy * 3], wB1 = w2B[dy * 3 + 1], wB2 = w2B[dy * 3 + 2];
    s0 = fmaf(hA[0], wA0, fmaf(hA[1], wA1, fmaf(hA[2], wA2, s0)));
    s0 = fmaf(hB[0], wB0, fmaf(hB[1], wB1, fmaf(hB[2], wB2, s0)));
    s1 = fmaf(hA[1], wA0, fmaf(hA[2], wA1, fmaf(hA[3], wA2, s1)));
    s1 = fmaf(hB[1], wB0, fmaf(hB[2], wB1, fmaf(hB[3], wB2, s1)));
    s2 = fmaf(hA[2], wA0, fmaf(hA[3], wA1, fmaf(hA[4], wA2, s2)));
    s2 = fmaf(hB[2], wB0, fmaf(hB[3], wB1, fmaf(hB[4], wB2, s2)));
    s3 = fmaf(hA[3], wA0, fmaf(hA[4], wA1, fmaf(hA[5], wA2, s3)));
    s3 = fmaf(hB[3], wB0, fmaf(hB[4], wB1, fmaf(hB[5], wB2, s3)));
  }
  float4 o4 = make_float4(s0, s1, s2, s3);
  *(float4*)(out + ((size_t)b * C_OUT + c) * HW + (ty0 + row2) * IMG + tx0 + oc0) = o4;
}

extern "C" void kernel_launch(void* const* d_in, const int* in_sizes, int n_in,
                              void* d_out, int out_size, void* d_ws, size_t ws_size,
                              hipStream_t stream) {
  const float* x     = (const float*)d_in[0];
  const float* pre_w = (const float*)d_in[1];
  const float* pre_b = (const float*)d_in[2];
  const float* gw0   = (const float*)d_in[3];
  const float* gb0   = (const float*)d_in[4];
  const float* gw1   = (const float*)d_in[5];
  const float* gb1   = (const float*)d_in[6];
  const float* ew1   = (const float*)d_in[7];
  const float* eb1   = (const float*)d_in[8];
  const float* ew2   = (const float*)d_in[9];
  const float* eb2   = (const float*)d_in[10];
  float* out = (float*)d_out;

  char* ws = (char*)d_ws;
  unsigned short* x1 = (unsigned short*)ws;             // bf16, 16.78 MB
  float* pmax   = (float*)(ws + 16777216);              // [512 strip][512 bo]
  float* psum   = (float*)(ws + 17825792);
  float* pooled = (float*)(ws + 18874368);              // 512 fp32
  float* cof    = (float*)(ws + 18876416);              // 32 fp32
  uint4* whi    = (uint4*)(ws + 18878464);              // 16 KB
  uint4* wlo    = (uint4*)(ws + 18894848);              // 16 KB

  wfrag_kernel<<<1, 64, 0, stream>>>(pre_w, whi, wlo);
  prefuse_mfma<<<4096, 64, 0, stream>>>(x, whi, wlo, pre_b, x1, pmax, psum);
  pool2_kernel<<<512, 64, 0, stream>>>(pmax, psum, pooled);
  gate_kernel<<<1, 64, 0, stream>>>(pooled, gw0, gb0, gw1, gb1, cof);
  expert_kernel<<<8192, 256, 0, stream>>>(x1, ew1, eb1, ew2, eb2, cof, out);
}

// Round 10
// 76.510 us; speedup vs baseline: 1.0147x; 1.0147x over previous
//
#include <hip/hip_runtime.h>
#include <hip/hip_bf16.h>
#include <math.h>

#define HW 16384          // 128*128
#define IMG 128
#define C_IN 128
#define C_OUT 64
#define NB 8
#define NE 4

typedef __attribute__((ext_vector_type(8))) short bf16x8;
typedef __attribute__((ext_vector_type(4))) float f32x4;

static __device__ __forceinline__ float bf2f_u(unsigned hbits) {
  union { unsigned u; float f; } v; v.u = hbits << 16;
  return v.f;
}
static __device__ __forceinline__ float bf2f(unsigned short h) {
  return bf2f_u((unsigned)h);
}
// HW packed conversion: two f32 -> one u32 of 2 bf16 (v_cvt_pk_bf16_f32)
static __device__ __forceinline__ unsigned cvtpk(float a, float b) {
  __hip_bfloat162 p = __float22bfloat162_rn(make_float2(a, b));
  union { __hip_bfloat162 h; unsigned u; } v; v.h = p;
  return v.u;
}
// Dekker split of a float pair
static __device__ __forceinline__ void pk2(float a, float b,
                                           unsigned& hi, unsigned& lo) {
  hi = cvtpk(a, b);
  float ra = a - bf2f_u(hi & 0xFFFFu);
  float rb = b - bf2f_u(hi >> 16);
  lo = cvtpk(ra, rb);
}

union FragU { unsigned u[4]; uint4 q; bf16x8 v; };

#define ASYNC_LOAD16(gsrc, ldst)                                              \
  __builtin_amdgcn_global_load_lds(                                           \
      (const __attribute__((address_space(1))) void*)(gsrc),                  \
      (__attribute__((address_space(3))) void*)(ldst), 16, 0, 0)

// ---- K0: precompute W MFMA fragments (hi/lo bf16), block-invariant ----
__global__ __launch_bounds__(64) void wfrag_kernel(
    const float* __restrict__ pre_w, uint4* __restrict__ whi,
    uint4* __restrict__ wlo) {
  int lane = threadIdx.x;
  int rowb = lane & 15, kg = lane >> 4;
  for (int q = 0; q < 16; ++q) {          // q = k*4 + ot
    int k = q >> 2, ot = q & 3;
    const float* wp = pre_w + (ot * 16 + rowb) * C_IN + k * 32 + kg * 8;
    float4 a = *(const float4*)wp;
    float4 c = *(const float4*)(wp + 4);
    uint4 h, l;
    pk2(a.x, a.y, h.x, l.x);
    pk2(a.z, a.w, h.y, l.y);
    pk2(c.x, c.y, h.z, l.z);
    pk2(c.z, c.w, h.w, l.w);
    whi[q * 64 + lane] = h;
    wlo[q * 64 + lane] = l;
  }
}

// ---- K1: pre-fuse 1x1 conv as MFMA GEMM, async-DMA X staging ----
// 1 wave/block, wave-private 2x4KB LDS double buffer, counted vmcnt, NO
// barriers in the K-loop. X layout in LDS: [ch_in_step][px-quad^swz][4].
// Swizzle (both sides): quad' = (px>>2) ^ (ch>>2)  -> <=2-way banks (free).
__global__ __launch_bounds__(64, 4) void prefuse_mfma(
    const float* __restrict__ x, const uint4* __restrict__ whi,
    const uint4* __restrict__ wlo, const float* __restrict__ pre_b,
    unsigned short* __restrict__ x1, float* __restrict__ pmax,
    float* __restrict__ psum) {
  __shared__ float xls[2][1024];            // 2 x 4KB k-step buffers
  __shared__ unsigned short tbuf[16][72];   // transpose buffer
  int lane = threadIdx.x;
  int rowb = lane & 15;                     // A-row(px) / B-col(o)
  int kg = lane >> 4;                       // k-group 0..3
  int blk = blockIdx.x;                     // 4096
  int b = blk >> 9;
  int strip = blk & 511;
  int px0 = strip << 5;                     // 32 px per strip

  const float* xbase = x + (size_t)b * C_IN * HW + px0;

  // stage k-step ks (32 ch x 32 px = 4KB) into buffer bf; source quad
  // pre-swizzled so LDS slot (ch, qs) holds global quad qs ^ (ch>>2).
#define STAGE(ks, bf)                                                         \
  {                                                                           \
    _Pragma("unroll")                                                         \
    for (int r = 0; r < 4; ++r) {                                             \
      int ch = (ks) * 32 + r * 8 + (lane >> 3);                               \
      int qs = (lane & 7) ^ ((r * 2 + (lane >> 5)) & 7);                      \
      ASYNC_LOAD16(xbase + (size_t)ch * HW + qs * 4, &xls[bf][r * 256]);      \
    }                                                                         \
  }

  STAGE(0, 0)

  f32x4 acc[2][4];                          // [px-tile][o-tile]
#pragma unroll
  for (int ot = 0; ot < 4; ++ot) {
    float t = pre_b[ot * 16 + rowb];
#pragma unroll
    for (int pt = 0; pt < 2; ++pt) acc[pt][ot] = (f32x4){t, t, t, t};
  }

#pragma unroll
  for (int k = 0; k < 4; ++k) {
    FragU wh[4], wl[4];
#pragma unroll
    for (int ot = 0; ot < 4; ++ot) {
      wh[ot].q = whi[(k * 4 + ot) * 64 + lane];
      wl[ot].q = wlo[(k * 4 + ot) * 64 + lane];
    }
    if (k < 3) {
      STAGE(k + 1, (k + 1) & 1)
      asm volatile("s_waitcnt vmcnt(4)" ::: "memory");  // buf k done; k+1 in flight
    } else {
      asm volatile("s_waitcnt vmcnt(0)" ::: "memory");
    }
    const float* xb = xls[k & 1];
#pragma unroll
    for (int pt = 0; pt < 2; ++pt) {
      float xv[8];
#pragma unroll
      for (int j = 0; j < 8; ++j) {
        int ch = kg * 8 + j;
        int qq = ((pt * 4 + (rowb >> 2)) ^ (ch >> 2)) & 7;
        xv[j] = xb[ch * 32 + qq * 4 + (rowb & 3)];
      }
      FragU h, l;
      pk2(xv[0], xv[1], h.u[0], l.u[0]);
      pk2(xv[2], xv[3], h.u[1], l.u[1]);
      pk2(xv[4], xv[5], h.u[2], l.u[2]);
      pk2(xv[6], xv[7], h.u[3], l.u[3]);
#pragma unroll
      for (int ot = 0; ot < 4; ++ot) {
        acc[pt][ot] = __builtin_amdgcn_mfma_f32_16x16x32_bf16(h.v, wh[ot].v, acc[pt][ot], 0, 0, 0);
        acc[pt][ot] = __builtin_amdgcn_mfma_f32_16x16x32_bf16(l.v, wh[ot].v, acc[pt][ot], 0, 0, 0);
        acc[pt][ot] = __builtin_amdgcn_mfma_f32_16x16x32_bf16(h.v, wl[ot].v, acc[pt][ot], 0, 0, 0);
      }
    }
  }
#undef STAGE

  // epilogue: pooling partials + LDS transpose -> bf16 x1 store
#pragma unroll
  for (int ot = 0; ot < 4; ++ot) {
    float m = -INFINITY, s = 0.f;
#pragma unroll
    for (int pt = 0; pt < 2; ++pt)
#pragma unroll
      for (int r = 0; r < 4; ++r) {
        float v = acc[pt][ot][r];
        m = fmaxf(m, v); s += v;
      }
    m = fmaxf(m, __shfl_xor(m, 16)); s += __shfl_xor(s, 16);
    m = fmaxf(m, __shfl_xor(m, 32)); s += __shfl_xor(s, 32);
    if (lane < 16) {
      int idx = strip * 512 + b * 64 + ot * 16 + lane;  // [strip][bo]
      pmax[idx] = m; psum[idx] = s;
    }
    // D: row(px) = pt*16 + kg*4 + r, col(o) = rowb
#pragma unroll
    for (int pt = 0; pt < 2; ++pt) {
      uint2 p;
      p.x = cvtpk(acc[pt][ot][0], acc[pt][ot][1]);
      p.y = cvtpk(acc[pt][ot][2], acc[pt][ot][3]);
      *(uint2*)&tbuf[rowb][pt * 16 + kg * 4] = p;
    }
    __syncthreads();  // 1-wave block: cheap ordering fence
    uint4 val = *(const uint4*)&tbuf[lane >> 2][(lane & 3) * 8];
    unsigned short* op = x1 + ((size_t)b * C_OUT + ot * 16 + (lane >> 2)) * HW
                            + px0 + (lane & 3) * 8;
    *(uint4*)op = val;
    __syncthreads();  // WAR guard before next ot reuses tbuf
  }
}

// ---- K2: finish pooling: one block per (b,o) ----
__global__ __launch_bounds__(64) void pool2_kernel(
    const float* __restrict__ pmax, const float* __restrict__ psum,
    float* __restrict__ pooled) {
  int bo = blockIdx.x;       // 0..511
  int lane = threadIdx.x;
  float m = -INFINITY, s = 0.f;
#pragma unroll
  for (int i = 0; i < 8; ++i) {
    int strip = lane + (i << 6);
    m = fmaxf(m, pmax[strip * 512 + bo]);
    s += psum[strip * 512 + bo];
  }
#pragma unroll
  for (int d = 32; d >= 1; d >>= 1) {
    m = fmaxf(m, __shfl_xor(m, d));
    s += __shfl_xor(s, d);
  }
  if (lane == 0) pooled[bo] = m + s * (1.0f / HW);
}

// ---- K3: gate network -> cof[B][E] ----
__global__ __launch_bounds__(64) void gate_kernel(
    const float* __restrict__ pooled, const float* __restrict__ gw0,
    const float* __restrict__ gb0, const float* __restrict__ gw1,
    const float* __restrict__ gb1, float* __restrict__ cof) {
  int b = threadIdx.x;
  if (b >= NB) return;
  float logits[NE], noise[NE];
#pragma unroll
  for (int e = 0; e < NE; ++e) {
    float d0 = gb0[e], d1 = gb1[e];
    for (int k = 0; k < C_OUT; ++k) {
      float pv = pooled[b * C_OUT + k];
      d0 = fmaf(pv, gw0[e * C_OUT + k], d0);
      d1 = fmaf(pv, gw1[e * C_OUT + k], d1);
    }
    logits[e] = d1 > 0.f ? d1 : 0.2f * d1;
    noise[e] = log1pf(expf(d0));
  }
  float mn = 0.25f * (noise[0] + noise[1] + noise[2] + noise[3]);
  float var = 0.f;
#pragma unroll
  for (int e = 0; e < NE; ++e) { float d = noise[e] - mn; var += d * d; }
  float sd = sqrtf(var * (1.0f / 3.0f));
  float scores[NE];
#pragma unroll
  for (int e = 0; e < NE; ++e) scores[e] = logits[e] + (noise[e] - mn) / sd;
  int i0 = 0;
#pragma unroll
  for (int e = 1; e < NE; ++e) if (scores[e] > scores[i0]) i0 = e;
  int i1 = -1;
#pragma unroll
  for (int e = 0; e < NE; ++e)
    if (e != i0 && (i1 < 0 || scores[e] > scores[i1])) i1 = e;
  float mm = fmaxf(logits[i0], logits[i1]);
  float e0 = expf(logits[i0] - mm), e1 = expf(logits[i1] - mm);
  float inv = 1.0f / (e0 + e1);
#pragma unroll
  for (int e = 0; e < NE; ++e) cof[b * NE + e] = 0.f;
  cof[b * NE + i0] = e0 * inv;
  cof[b * NE + i1] = e1 * inv;
}

// ---- K4: fused experts, single pass over BOTH active experts ----
__global__ __launch_bounds__(256) void expert_kernel(
    const unsigned short* __restrict__ x1, const float* __restrict__ ew1,
    const float* __restrict__ eb1, const float* __restrict__ ew2,
    const float* __restrict__ eb2, const float* __restrict__ cof,
    float* __restrict__ out) {
  __shared__ float xs[36 * 36 + 8];
  __shared__ unsigned hs[34 * 36 + 8];     // packed (hA | hB<<16)
  int tid = threadIdx.x, blk = blockIdx.x;
  int tile = blk & 15, c = (blk >> 4) & 63, b = blk >> 10;
  int ty0 = (tile >> 2) * 32, tx0 = (tile & 3) * 32;
  const unsigned short* xp = x1 + ((size_t)b * C_OUT + c) * HW;

  // the two active experts (uniform per block)
  int eA = -1, eB = -1; float cfA = 0.f, cfB = 0.f;
#pragma unroll
  for (int e = 0; e < NE; ++e) {
    float cv = cof[b * NE + e];
    if (cv != 0.f) { if (eA < 0) { eA = e; cfA = cv; } else { eB = e; cfB = cv; } }
  }
  if (eA < 0) { eA = 0; cfA = 0.f; }
  if (eB < 0) { eB = eA; cfB = 0.f; }

  float w1A[9], w1B[9], w2A[9], w2B[9];
#pragma unroll
  for (int t = 0; t < 9; ++t) {
    w1A[t] = ew1[((size_t)eA * C_OUT + c) * 9 + t];
    w1B[t] = ew1[((size_t)eB * C_OUT + c) * 9 + t];
    w2A[t] = cfA * ew2[((size_t)eA * C_OUT + c) * 9 + t];
    w2B[t] = cfB * ew2[((size_t)eB * C_OUT + c) * 9 + t];
  }
  float b1A = eb1[eA * C_OUT + c], b1B = eb1[eB * C_OUT + c];
  float bias2 = cfA * eb2[eA * C_OUT + c] + cfB * eb2[eB * C_OUT + c];

  // stage 36x36 x-tile (halo 2), zero outside image
  for (int i = tid; i < 36 * 36; i += 256) {
    int iy = i / 36, ix = i - iy * 36;
    int gy = ty0 - 2 + iy, gx = tx0 - 2 + ix;
    float v = 0.f;
    if ((unsigned)gy < 128u && (unsigned)gx < 128u) v = bf2f(xp[gy * IMG + gx]);
    xs[i] = v;
  }
  __syncthreads();

  // conv1 + gelu for BOTH experts; pack as bf16 pair
  for (int t = tid; t < 34 * 9; t += 256) {
    int hr = t / 9, g4 = t - hr * 9;
    int hc0 = g4 * 4;
    const float* xr = xs + hr * 36 + hc0;
    float xv[3][6];
#pragma unroll
    for (int dy = 0; dy < 3; ++dy) {
      float4 a = *(const float4*)(xr + dy * 36);
      float2 bb = *(const float2*)(xr + dy * 36 + 4);
      xv[dy][0] = a.x; xv[dy][1] = a.y; xv[dy][2] = a.z; xv[dy][3] = a.w;
      xv[dy][4] = bb.x; xv[dy][5] = bb.y;
    }
    int gy = ty0 - 1 + hr, gx0 = tx0 - 1 + hc0;
    uint4 hv; unsigned* hp4 = (unsigned*)&hv;
#pragma unroll
    for (int j = 0; j < 4; ++j) {
      float sA = b1A, sB = b1B;
#pragma unroll
      for (int dy = 0; dy < 3; ++dy)
#pragma unroll
        for (int dx = 0; dx < 3; ++dx) {
          float xvv = xv[dy][j + dx];
          sA = fmaf(xvv, w1A[dy * 3 + dx], sA);
          sB = fmaf(xvv, w1B[dy * 3 + dx], sB);
        }
      float uA = sA * sA, uB = sB * sB;
      float tA = 1.f - uA * (0.16666667f - uA * (0.025f - uA * 0.0029761905f));
      float tB = 1.f - uB * (0.16666667f - uB * (0.025f - uB * 0.0029761905f));
      float gA = sA * fmaf(0.3989422804f * sA, tA, 0.5f);
      float gB = sB * fmaf(0.3989422804f * sB, tB, 0.5f);
      bool ok = ((unsigned)gy < 128u) && ((unsigned)(gx0 + j) < 128u);
      hp4[j] = ok ? cvtpk(gA, gB) : 0u;
    }
    *(uint4*)(hs + hr * 36 + hc0) = hv;
  }
  __syncthreads();

  // conv2 combined: 4 outputs per thread
  int row2 = tid >> 3, oc0 = (tid & 7) * 4;
  const unsigned* hp = hs + row2 * 36 + oc0;
  float s0 = bias2, s1 = bias2, s2 = bias2, s3 = bias2;
#pragma unroll
  for (int dy = 0; dy < 3; ++dy) {
    uint4 a = *(const uint4*)(hp + dy * 36);
    uint2 bb = *(const uint2*)(hp + dy * 36 + 4);
    unsigned u[6] = {a.x, a.y, a.z, a.w, bb.x, bb.y};
    float hA[6], hB[6];
#pragma unroll
    for (int q = 0; q < 6; ++q) {
      hA[q] = bf2f_u(u[q] & 0xFFFFu);
      union { unsigned uu; float ff; } vb; vb.uu = u[q] & 0xFFFF0000u;
      hB[q] = vb.ff;
    }
    float wA0 = w2A[dy * 3], wA1 = w2A[dy * 3 + 1], wA2 = w2A[dy * 3 + 2];
    float wB0 = w2B[dy * 3], wB1 = w2B[dy * 3 + 1], wB2 = w2B[dy * 3 + 2];
    s0 = fmaf(hA[0], wA0, fmaf(hA[1], wA1, fmaf(hA[2], wA2, s0)));
    s0 = fmaf(hB[0], wB0, fmaf(hB[1], wB1, fmaf(hB[2], wB2, s0)));
    s1 = fmaf(hA[1], wA0, fmaf(hA[2], wA1, fmaf(hA[3], wA2, s1)));
    s1 = fmaf(hB[1], wB0, fmaf(hB[2], wB1, fmaf(hB[3], wB2, s1)));
    s2 = fmaf(hA[2], wA0, fmaf(hA[3], wA1, fmaf(hA[4], wA2, s2)));
    s2 = fmaf(hB[2], wB0, fmaf(hB[3], wB1, fmaf(hB[4], wB2, s2)));
    s3 = fmaf(hA[3], wA0, fmaf(hA[4], wA1, fmaf(hA[5], wA2, s3)));
    s3 = fmaf(hB[3], wB0, fmaf(hB[4], wB1, fmaf(hB[5], wB2, s3)));
  }
  float4 o4 = make_float4(s0, s1, s2, s3);
  *(float4*)(out + ((size_t)b * C_OUT + c) * HW + (ty0 + row2) * IMG + tx0 + oc0) = o4;
}

extern "C" void kernel_launch(void* const* d_in, const int* in_sizes, int n_in,
                              void* d_out, int out_size, void* d_ws, size_t ws_size,
                              hipStream_t stream) {
  const float* x     = (const float*)d_in[0];
  const float* pre_w = (const float*)d_in[1];
  const float* pre_b = (const float*)d_in[2];
  const float* gw0   = (const float*)d_in[3];
  const float* gb0   = (const float*)d_in[4];
  const float* gw1   = (const float*)d_in[5];
  const float* gb1   = (const float*)d_in[6];
  const float* ew1   = (const float*)d_in[7];
  const float* eb1   = (const float*)d_in[8];
  const float* ew2   = (const float*)d_in[9];
  const float* eb2   = (const float*)d_in[10];
  float* out = (float*)d_out;

  char* ws = (char*)d_ws;
  unsigned short* x1 = (unsigned short*)ws;             // bf16, 16.78 MB
  float* pmax   = (float*)(ws + 16777216);              // [512 strip][512 bo]
  float* psum   = (float*)(ws + 17825792);
  float* pooled = (float*)(ws + 18874368);              // 512 fp32
  float* cof    = (float*)(ws + 18876416);              // 32 fp32
  uint4* whi    = (uint4*)(ws + 18878464);              // 16 KB
  uint4* wlo    = (uint4*)(ws + 18894848);              // 16 KB

  wfrag_kernel<<<1, 64, 0, stream>>>(pre_w, whi, wlo);
  prefuse_mfma<<<4096, 64, 0, stream>>>(x, whi, wlo, pre_b, x1, pmax, psum);
  pool2_kernel<<<512, 64, 0, stream>>>(pmax, psum, pooled);
  gate_kernel<<<1, 64, 0, stream>>>(pooled, gw0, gb0, gw1, gb1, cof);
  expert_kernel<<<8192, 256, 0, stream>>>(x1, ew1, eb1, ew2, eb2, cof, out);
}